// Round 3
// baseline (341.780 us; speedup 1.0000x reference)
//
#include <hip/hip_runtime.h>

#define B_ 256
#define N_IN 1152
#define N_OUT 10
#define D_IN 8
#define D_OUT 16
#define OJ 160                     // N_OUT * D_OUT
#define SN (B_*OJ)                 // 40960
#define LOG2E 1.44269504088896340736f
#define PNC 8                      // n's per wave per pass kernel
#define NGX (N_IN/PNC)             // 144

typedef __attribute__((ext_vector_type(8))) short bf16x8;
typedef __attribute__((ext_vector_type(4))) float f32x4;

#define NW_ELEMS (N_IN*N_OUT*D_OUT)      // 184320 rows of 8
#define NX_ELEMS (B_*N_IN)               // 294912 rows of 8

// ---- bf16 split helpers (RNE) ----
__device__ __forceinline__ unsigned short f2bf(float f) {
  unsigned u = __float_as_uint(f);
  u += 0x7fffu + ((u >> 16) & 1u);
  return (unsigned short)(u >> 16);
}
__device__ __forceinline__ float bf2f(unsigned short s) {
  return __uint_as_float(((unsigned)s) << 16);
}

// ---- DPP rotate-reduce over 16-lane row (finish kernel) ----
template<int CTRL>
__device__ __forceinline__ float dpp_add(float x) {
  int y = __builtin_amdgcn_mov_dpp(__float_as_int(x), CTRL, 0xF, 0xF, false);
  return x + __int_as_float(y);
}
__device__ __forceinline__ float row_sum16(float x) {
  x = dpp_add<0x128>(x); x = dpp_add<0x124>(x);
  x = dpp_add<0x122>(x); x = dpp_add<0x121>(x);
  return x;
}

// ---- pack W (1152,10,16,8) f32 -> WH/WL bf16, same flattening ----
__global__ __launch_bounds__(256) void pack_W(const float* __restrict__ W,
                                              short* __restrict__ WH,
                                              short* __restrict__ WL) {
  const int t = blockIdx.x*256 + threadIdx.x;          // < 184320
  const float4 a = ((const float4*)W)[t*2];
  const float4 b = ((const float4*)W)[t*2+1];
  const float w[8] = {a.x,a.y,a.z,a.w,b.x,b.y,b.z,b.w};
  bf16x8 vh, vl;
#pragma unroll
  for (int e=0;e<8;e++){
    unsigned short hh = f2bf(w[e]);
    vh[e] = (short)hh;
    vl[e] = (short)f2bf(w[e] - bf2f(hh));
  }
  ((bf16x8*)WH)[t] = vh;
  ((bf16x8*)WL)[t] = vl;
}

// ---- pack x (256,1152,8) f32 -> XH/XL bf16 in [n][b][8] layout ----
__global__ __launch_bounds__(256) void pack_x(const float* __restrict__ x,
                                              short* __restrict__ XH,
                                              short* __restrict__ XL) {
  const int t = blockIdx.x*256 + threadIdx.x;          // < 294912, t = b*1152+n
  const int b = t / N_IN, n = t % N_IN;
  const float4 a = ((const float4*)x)[t*2];
  const float4 c = ((const float4*)x)[t*2+1];
  const float w[8] = {a.x,a.y,a.z,a.w,c.x,c.y,c.z,c.w};
  bf16x8 vh, vl;
#pragma unroll
  for (int e=0;e<8;e++){
    unsigned short hh = f2bf(w[e]);
    vh[e] = (short)hh;
    vl[e] = (short)f2bf(w[e] - bf2f(hh));
  }
  const int o = n*B_ + b;
  ((bf16x8*)XH)[o] = vh;
  ((bf16x8*)XL)[o] = vl;
}

__global__ __launch_bounds__(256) void caps_zero(float* __restrict__ s) {
  s[blockIdx.x*256 + threadIdx.x] = 0.f;
}

// ---- pass 1: s += sum_n u (uniform coupling; 0.1 folded into finish) ----
__global__ __launch_bounds__(256,4) void pass1(const short* __restrict__ WH,
                                               const short* __restrict__ WL,
                                               const short* __restrict__ XH,
                                               const short* __restrict__ XL,
                                               float* __restrict__ s) {
  const int tid = threadIdx.x;
  const int w = tid >> 6, l = tid & 63;
  const int bb = l & 15, c = l >> 4;
  const int b0 = (blockIdx.y*4 + w) * 16;
  const int n0 = blockIdx.x * PNC;
  // K-chunks: A=[Wh,Wl,Wh,Wl], B=[xh,xh,xl,xl]  => exact (Wh+Wl)(xh+xl)
  const short* Abase = (c & 1)  ? WL : WH;
  const short* Bbase = (c >> 1) ? XL : XH;

  f32x4 acc[N_OUT];
  const f32x4 zz = {0.f,0.f,0.f,0.f};
#pragma unroll
  for (int o=0;o<N_OUT;o++) acc[o] = zz;

  for (int nn=0; nn<PNC; ++nn) {
    const int n = n0 + nn;
    const bf16x8 bfrag = *(const bf16x8*)&Bbase[((size_t)n*B_ + b0 + bb)*8];
    const short* Ap = &Abase[(size_t)n*1280 + bb*8];   // row j = l&15
#pragma unroll
    for (int o=0;o<N_OUT;o++) {
      const bf16x8 afrag = *(const bf16x8*)&Ap[o*128];
      acc[o] = __builtin_amdgcn_mfma_f32_16x16x32_bf16(afrag, bfrag, acc[o], 0,0,0);
    }
  }
  // C layout: col=lane&15 (=b), row=(lane>>4)*4+e (=j)
  float* sp = &s[(size_t)(b0+bb)*OJ + c*4];
#pragma unroll
  for (int o=0;o<N_OUT;o++)
#pragma unroll
    for (int e=0;e<4;e++)
      unsafeAtomicAdd(&sp[o*16 + e], acc[o][e]);
}

// ---- pass 2/3: u via MFMA, logits = u.veff (veff pre-scaled by log2e), softmax, acc ----
__global__ __launch_bounds__(256,3) void pass23(const short* __restrict__ WH,
                                                const short* __restrict__ WL,
                                                const short* __restrict__ XH,
                                                const short* __restrict__ XL,
                                                const float* __restrict__ veff,
                                                float* __restrict__ s) {
  const int tid = threadIdx.x;
  const int w = tid >> 6, l = tid & 63;
  const int bb = l & 15, c = l >> 4;
  const int b0 = (blockIdx.y*4 + w) * 16;
  const int n0 = blockIdx.x * PNC;
  const short* Abase = (c & 1)  ? WL : WH;
  const short* Bbase = (c >> 1) ? XL : XH;

  f32x4 vj[N_OUT], acc[N_OUT];
  const f32x4 zz = {0.f,0.f,0.f,0.f};
  const float* vp = &veff[(size_t)(b0+bb)*OJ + c*4];
#pragma unroll
  for (int o=0;o<N_OUT;o++) { vj[o] = *(const f32x4*)&vp[o*16]; acc[o] = zz; }

  for (int nn=0; nn<PNC; ++nn) {
    const int n = n0 + nn;
    const bf16x8 bfrag = *(const bf16x8*)&Bbase[((size_t)n*B_ + b0 + bb)*8];
    const short* Ap = &Abase[(size_t)n*1280 + bb*8];
    f32x4 u[N_OUT];
#pragma unroll
    for (int o=0;o<N_OUT;o++) {
      const bf16x8 afrag = *(const bf16x8*)&Ap[o*128];
      u[o] = __builtin_amdgcn_mfma_f32_16x16x32_bf16(afrag, bfrag, zz, 0,0,0);
    }
    // logits (already in log2 domain since veff = v*log2e)
    float ez[N_OUT], Z = 0.f;
#pragma unroll
    for (int o=0;o<N_OUT;o++) {
      float t = u[o][0]*vj[o][0] + u[o][1]*vj[o][1]
              + u[o][2]*vj[o][2] + u[o][3]*vj[o][3];
      t += __shfl_xor(t, 16);
      t += __shfl_xor(t, 32);
      ez[o] = exp2f(t);
      Z += ez[o];
    }
    const float invZ = 1.f / Z;
#pragma unroll
    for (int o=0;o<N_OUT;o++) {
      const float cc = ez[o] * invZ;
      acc[o] += cc * u[o];
    }
  }
  float* sp = &s[(size_t)(b0+bb)*OJ + c*4];
#pragma unroll
  for (int o=0;o<N_OUT;o++)
#pragma unroll
    for (int e=0;e<4;e++)
      unsafeAtomicAdd(&sp[o*16 + e], acc[o][e]);
}

// ---- squash + optional vprev add; vout scaled by lscale (log2e for pass inputs) ----
__global__ __launch_bounds__(256) void finish(float* __restrict__ s, float scale,
                                              const float* __restrict__ vprev,
                                              float* __restrict__ vout,
                                              int zero_s, float lscale) {
  const int idx = blockIdx.x*256 + threadIdx.x;
  const float t = s[idx] * scale;
  const float sq = row_sum16(t * t);
  float v = t * (sq / (1.f + sq)) * rsqrtf(sq + 1e-8f);
  v *= lscale;
  if (vprev != nullptr) v += vprev[idx];
  vout[idx] = v;
  if (zero_s) s[idx] = 0.f;
}

extern "C" void kernel_launch(void* const* d_in, const int* in_sizes, int n_in,
                              void* d_out, int out_size, void* d_ws, size_t ws_size,
                              hipStream_t stream) {
  const float* x = (const float*)d_in[0];   // (256,1152,8)
  const float* W = (const float*)d_in[1];   // (1,1152,10,16,8)
  float* out = (float*)d_out;               // (256,10,16)

  float* s   = (float*)d_ws;
  float* v1  = s  + SN;                     // stored * log2e
  float* v12 = v1 + SN;                     // stored * log2e
  short* WH = (short*)(v12 + SN);
  short* WL = WH + (size_t)NW_ELEMS*8;
  short* XH = WL + (size_t)NW_ELEMS*8;
  short* XL = XH + (size_t)NX_ELEMS*8;      // total ws ~= 15.8 MB

  pack_W<<<NW_ELEMS/256, 256, 0, stream>>>(W, WH, WL);
  pack_x<<<NX_ELEMS/256, 256, 0, stream>>>(x, XH, XL);
  caps_zero<<<SN/256, 256, 0, stream>>>(s);

  const dim3 pg(NGX, 4), blk(256);

  // iter 1: uniform c -> s1 ; v1 = squash(0.1*s1)*log2e ; s := 0
  pass1<<<pg, blk, 0, stream>>>(WH, WL, XH, XL, s);
  finish<<<SN/256, 256, 0, stream>>>(s, 0.1f, nullptr, v1, 1, LOG2E);

  // iter 2: logits = u.v1 -> s2 ; v12 = v1 + squash(s2)*log2e ; s := 0
  pass23<<<pg, blk, 0, stream>>>(WH, WL, XH, XL, v1, s);
  finish<<<SN/256, 256, 0, stream>>>(s, 1.0f, v1, v12, 1, LOG2E);

  // iter 3: logits = u.(v1+v2) -> s3 ; out = squash(s3) (natural scale)
  pass23<<<pg, blk, 0, stream>>>(WH, WL, XH, XL, v12, s);
  finish<<<SN/256, 256, 0, stream>>>(s, 1.0f, nullptr, out, 0, 1.0f);
}

// Round 4
// 118.439 us; speedup vs baseline: 2.8857x; 2.8857x over previous
//
#include <hip/hip_runtime.h>

#define B_ 256
#define N_IN 1152
#define N_OUT 10
#define D_OUT 16
#define OJ 160                     // N_OUT * D_OUT
#define SN (B_*OJ)                 // 40960
#define LOG2E 1.44269504088896340736f
#define PNC 16                     // n's per wave
#define NGB (N_IN/PNC)             // 72 n-groups (partials)

typedef __attribute__((ext_vector_type(8))) short bf16x8;
typedef __attribute__((ext_vector_type(4))) float f32x4;

#define NW_ELEMS (N_IN*N_OUT*D_OUT)      // 184320 rows of 8 (W)
#define NX_ELEMS (B_*N_IN)               // 294912 rows of 8 (x)
#define NWB (NW_ELEMS/256)               // 720 blocks
#define NXB (NX_ELEMS/256)               // 1152 blocks

// ---- bf16 split helpers (RNE) ----
__device__ __forceinline__ unsigned short f2bf(float f) {
  unsigned u = __float_as_uint(f);
  u += 0x7fffu + ((u >> 16) & 1u);
  return (unsigned short)(u >> 16);
}
__device__ __forceinline__ float bf2f(unsigned short s) {
  return __uint_as_float(((unsigned)s) << 16);
}

// ---- DPP rotate-reduce over 16-lane row (finish kernel) ----
template<int CTRL>
__device__ __forceinline__ float dpp_add(float x) {
  int y = __builtin_amdgcn_mov_dpp(__float_as_int(x), CTRL, 0xF, 0xF, false);
  return x + __int_as_float(y);
}
__device__ __forceinline__ float row_sum16(float x) {
  x = dpp_add<0x128>(x); x = dpp_add<0x124>(x);
  x = dpp_add<0x122>(x); x = dpp_add<0x121>(x);
  return x;
}

// ---- single prep kernel: split W and x into bf16 hi/lo ----
__global__ __launch_bounds__(256) void pack_all(const float* __restrict__ W,
                                                const float* __restrict__ x,
                                                short* __restrict__ WH, short* __restrict__ WL,
                                                short* __restrict__ XH, short* __restrict__ XL) {
  const int bid = blockIdx.x;
  if (bid < NWB) {
    const int t = bid*256 + threadIdx.x;
    const float4 a = ((const float4*)W)[t*2];
    const float4 b = ((const float4*)W)[t*2+1];
    const float w[8] = {a.x,a.y,a.z,a.w,b.x,b.y,b.z,b.w};
    bf16x8 vh, vl;
#pragma unroll
    for (int e=0;e<8;e++){
      unsigned short hh = f2bf(w[e]);
      vh[e] = (short)hh;
      vl[e] = (short)f2bf(w[e] - bf2f(hh));
    }
    ((bf16x8*)WH)[t] = vh;
    ((bf16x8*)WL)[t] = vl;
  } else {
    const int t = (bid - NWB)*256 + threadIdx.x;     // t = b*1152 + n
    const int b = t / N_IN, n = t % N_IN;
    const float4 a = ((const float4*)x)[t*2];
    const float4 c = ((const float4*)x)[t*2+1];
    const float w[8] = {a.x,a.y,a.z,a.w,c.x,c.y,c.z,c.w};
    bf16x8 vh, vl;
#pragma unroll
    for (int e=0;e<8;e++){
      unsigned short hh = f2bf(w[e]);
      vh[e] = (short)hh;
      vl[e] = (short)f2bf(w[e] - bf2f(hh));
    }
    const int o = n*B_ + b;                          // [n][b][8] layout
    ((bf16x8*)XH)[o] = vh;
    ((bf16x8*)XL)[o] = vl;
  }
}

// K-chunk trick: one 16x16x32 MFMA; K-slices c=0..3 pull A from [WH,WL,WH,WL]
// and B from [XH,XH,XL,XL] => exact (Wh+Wl)(xh+xl). C: col=lane&15=b, row=c*4+e=j.

// ---- pass 1: uniform coupling; partial over PNC n's -> P[ng] ----
__global__ __launch_bounds__(64) void pass1(const short* __restrict__ WH,
                                            const short* __restrict__ WL,
                                            const short* __restrict__ XH,
                                            const short* __restrict__ XL,
                                            float* __restrict__ P) {
  const int l = threadIdx.x;
  const int bb = l & 15, c = l >> 4;
  const int b0 = blockIdx.y * 16;
  const int n0 = blockIdx.x * PNC;
  const short* Abase = (c & 1)  ? WL : WH;
  const short* Bbase = (c >> 1) ? XL : XH;

  f32x4 acc[N_OUT];
  const f32x4 zz = {0.f,0.f,0.f,0.f};
#pragma unroll
  for (int o=0;o<N_OUT;o++) acc[o] = zz;

  for (int nn=0; nn<PNC; ++nn) {
    const int n = n0 + nn;
    const bf16x8 bfrag = *(const bf16x8*)&Bbase[((size_t)n*B_ + b0 + bb)*8];
    const short* Ap = &Abase[(size_t)n*1280 + bb*8];
#pragma unroll
    for (int o=0;o<N_OUT;o++) {
      const bf16x8 afrag = *(const bf16x8*)&Ap[o*128];
      acc[o] = __builtin_amdgcn_mfma_f32_16x16x32_bf16(afrag, bfrag, acc[o], 0,0,0);
    }
  }
  float* Pp = &P[((size_t)blockIdx.x*B_ + b0 + bb)*OJ + c*4];
#pragma unroll
  for (int o=0;o<N_OUT;o++) *(f32x4*)&Pp[o*16] = acc[o];
}

// ---- pass 2/3: u via MFMA, logits = u.veff (veff pre-scaled by log2e), softmax, partial ----
__global__ __launch_bounds__(64) void pass23(const short* __restrict__ WH,
                                             const short* __restrict__ WL,
                                             const short* __restrict__ XH,
                                             const short* __restrict__ XL,
                                             const float* __restrict__ veff,
                                             float* __restrict__ P) {
  const int l = threadIdx.x;
  const int bb = l & 15, c = l >> 4;
  const int b0 = blockIdx.y * 16;
  const int n0 = blockIdx.x * PNC;
  const short* Abase = (c & 1)  ? WL : WH;
  const short* Bbase = (c >> 1) ? XL : XH;

  f32x4 vj[N_OUT], acc[N_OUT];
  const f32x4 zz = {0.f,0.f,0.f,0.f};
  const float* vp = &veff[(size_t)(b0+bb)*OJ + c*4];
#pragma unroll
  for (int o=0;o<N_OUT;o++) { vj[o] = *(const f32x4*)&vp[o*16]; acc[o] = zz; }

  for (int nn=0; nn<PNC; ++nn) {
    const int n = n0 + nn;
    const bf16x8 bfrag = *(const bf16x8*)&Bbase[((size_t)n*B_ + b0 + bb)*8];
    const short* Ap = &Abase[(size_t)n*1280 + bb*8];
    f32x4 u[N_OUT];
#pragma unroll
    for (int o=0;o<N_OUT;o++) {
      const bf16x8 afrag = *(const bf16x8*)&Ap[o*128];
      u[o] = __builtin_amdgcn_mfma_f32_16x16x32_bf16(afrag, bfrag, zz, 0,0,0);
    }
    // logit rows live split across c-groups: in-thread dot4 + xor16 + xor32
    float ez[N_OUT], Z = 0.f;
#pragma unroll
    for (int o=0;o<N_OUT;o++) {
      float t = u[o][0]*vj[o][0] + u[o][1]*vj[o][1]
              + u[o][2]*vj[o][2] + u[o][3]*vj[o][3];
      t += __shfl_xor(t, 16);
      t += __shfl_xor(t, 32);
      ez[o] = exp2f(t);          // veff already in log2 domain
      Z += ez[o];
    }
    const float invZ = 1.f / Z;
#pragma unroll
    for (int o=0;o<N_OUT;o++) acc[o] += (ez[o] * invZ) * u[o];
  }
  float* Pp = &P[((size_t)blockIdx.x*B_ + b0 + bb)*OJ + c*4];
#pragma unroll
  for (int o=0;o<N_OUT;o++) *(f32x4*)&Pp[o*16] = acc[o];
}

// ---- reduce partials over NGB + squash (+ optional vprev, output scaling) ----
__global__ __launch_bounds__(256) void finish(const float* __restrict__ P, float scale,
                                              const float* __restrict__ vprev,
                                              float* __restrict__ vout, float lscale) {
  const int idx = blockIdx.x*256 + threadIdx.x;      // b*160 + o*16 + j
  float t = 0.f;
#pragma unroll 8
  for (int g=0; g<NGB; ++g) t += P[(size_t)g*SN + idx];
  t *= scale;
  const float sq = row_sum16(t * t);                 // ||s||^2 over j
  float v = t * (sq / (1.f + sq)) * rsqrtf(sq + 1e-8f);
  v *= lscale;
  if (vprev != nullptr) v += vprev[idx];
  vout[idx] = v;
}

extern "C" void kernel_launch(void* const* d_in, const int* in_sizes, int n_in,
                              void* d_out, int out_size, void* d_ws, size_t ws_size,
                              hipStream_t stream) {
  const float* x = (const float*)d_in[0];   // (256,1152,8)
  const float* W = (const float*)d_in[1];   // (1,1152,10,16,8)
  float* out = (float*)d_out;               // (256,10,16)

  float* P   = (float*)d_ws;                // NGB*SN floats = 11.8 MB
  float* v1  = P  + (size_t)NGB*SN;         // stored * log2e
  float* v12 = v1 + SN;                     // stored * log2e
  short* WH = (short*)(v12 + SN);
  short* WL = WH + (size_t)NW_ELEMS*8;
  short* XH = WL + (size_t)NW_ELEMS*8;
  short* XL = XH + (size_t)NX_ELEMS*8;      // total ws ~= 27.5 MB

  pack_all<<<NWB + NXB, 256, 0, stream>>>(W, x, WH, WL, XH, XL);

  const dim3 pg(NGB, 16), pb(64);

  // iter 1: uniform c -> P ; v1 = squash(0.1*s1)*log2e
  pass1<<<pg, pb, 0, stream>>>(WH, WL, XH, XL, P);
  finish<<<SN/256, 256, 0, stream>>>(P, 0.1f, nullptr, v1, LOG2E);

  // iter 2: logits = u.v1 -> P ; v12 = v1 + squash(s2)*log2e
  pass23<<<pg, pb, 0, stream>>>(WH, WL, XH, XL, v1, P);
  finish<<<SN/256, 256, 0, stream>>>(P, 1.0f, v1, v12, LOG2E);

  // iter 3: logits = u.(v1+v2) -> P ; out = squash(s3)
  pass23<<<pg, pb, 0, stream>>>(WH, WL, XH, XL, v12, P);
  finish<<<SN/256, 256, 0, stream>>>(P, 1.0f, nullptr, out, 1.0f);
}

// Round 5
// 88.594 us; speedup vs baseline: 3.8578x; 1.3369x over previous
//
#include <hip/hip_runtime.h>

#define B_ 256
#define N_IN 1152
#define N_OUT 10
#define D_OUT 16
#define OJ 160                     // N_OUT * D_OUT
#define SN (B_*OJ)                 // 40960
#define LOG2E 1.44269504088896340736f
#define NPB 16                     // n's per block
#define NPW 4                      // n's per wave (4 waves/block)
#define NGB (N_IN/NPB)             // 72 partial groups

typedef __attribute__((ext_vector_type(8))) short bf16x8;
typedef __attribute__((ext_vector_type(4))) float f32x4;

#define NW_ELEMS (N_IN*N_OUT*D_OUT)      // 184320 rows of 8 (W)
#define NWB (NW_ELEMS/256)               // 720 W-pack blocks
#define XTB ((N_IN/16)*(B_/16))          // 72*16 = 1152 x-transpose blocks

// ---- bf16 split helpers (RNE) ----
__device__ __forceinline__ unsigned short f2bf(float f) {
  unsigned u = __float_as_uint(f);
  u += 0x7fffu + ((u >> 16) & 1u);
  return (unsigned short)(u >> 16);
}
__device__ __forceinline__ float bf2f(unsigned short s) {
  return __uint_as_float(((unsigned)s) << 16);
}

// ---- DPP rotate-reduce over 16-lane row (finish kernel) ----
template<int CTRL>
__device__ __forceinline__ float dpp_add(float x) {
  int y = __builtin_amdgcn_mov_dpp(__float_as_int(x), CTRL, 0xF, 0xF, false);
  return x + __int_as_float(y);
}
__device__ __forceinline__ float row_sum16(float x) {
  x = dpp_add<0x128>(x); x = dpp_add<0x124>(x);
  x = dpp_add<0x122>(x); x = dpp_add<0x121>(x);
  return x;
}

// ---- prep: split W (linear) and x (16x16 LDS transpose -> [n][b]) into bf16 hi/lo ----
__global__ __launch_bounds__(256) void pack_all(const float* __restrict__ W,
                                                const float* __restrict__ x,
                                                short* __restrict__ WH, short* __restrict__ WL,
                                                short* __restrict__ XH, short* __restrict__ XL) {
  const int bid = blockIdx.x;
  const int tid = threadIdx.x;
  if (bid < NWB) {
    const int t = bid*256 + tid;
    const float4 a = ((const float4*)W)[t*2];
    const float4 b = ((const float4*)W)[t*2+1];
    const float w[8] = {a.x,a.y,a.z,a.w,b.x,b.y,b.z,b.w};
    bf16x8 vh, vl;
#pragma unroll
    for (int e=0;e<8;e++){
      unsigned short hh = f2bf(w[e]);
      vh[e] = (short)hh;
      vl[e] = (short)f2bf(w[e] - bf2f(hh));
    }
    ((bf16x8*)WH)[t] = vh;
    ((bf16x8*)WL)[t] = vl;
  } else {
    __shared__ bf16x8 TH[16*17], TL[16*17];
    const int bid2 = bid - NWB;
    const int nt = bid2 >> 4, bt = bid2 & 15;
    // read phase: nn fastest -> coalesced 32B/lane reads of x
    const int nn = tid & 15, bb = tid >> 4;
    const size_t r = (size_t)((bt*16 + bb)*N_IN + nt*16 + nn);
    const float4 a = ((const float4*)x)[r*2];
    const float4 c = ((const float4*)x)[r*2+1];
    const float w[8] = {a.x,a.y,a.z,a.w,c.x,c.y,c.z,c.w};
    bf16x8 vh, vl;
#pragma unroll
    for (int e=0;e<8;e++){
      unsigned short hh = f2bf(w[e]);
      vh[e] = (short)hh;
      vl[e] = (short)f2bf(w[e] - bf2f(hh));
    }
    TH[nn*17 + bb] = vh;
    TL[nn*17 + bb] = vl;
    __syncthreads();
    // write phase: bb2 fastest -> coalesced 16B/lane stores of XH/XL [n][b]
    const int bb2 = tid & 15, nn2 = tid >> 4;
    const size_t o = (size_t)(nt*16 + nn2)*B_ + bt*16 + bb2;
    ((bf16x8*)XH)[o] = TH[nn2*17 + bb2];
    ((bf16x8*)XL)[o] = TL[nn2*17 + bb2];
  }
}

// K-chunk trick: one 16x16x32 MFMA; lane's K-chunk c=lane>>4 pulls A from
// [WH,WL,WH,WL] and B from [XH,XH,XL,XL] => exact (Wh+Wl)(xh+xl).
// C layout: col=lane&15=b, row=c*4+e=j.

// ---- pass 1: uniform coupling; 4 waves/block, LDS tree -> P[72 groups] ----
__global__ __launch_bounds__(256) void pass1(const short* __restrict__ WH,
                                             const short* __restrict__ WL,
                                             const short* __restrict__ XH,
                                             const short* __restrict__ XL,
                                             float* __restrict__ P) {
  __shared__ f32x4 red[3*640];         // 30 KB
  const int tid = threadIdx.x, w = tid >> 6, l = tid & 63;
  const int bb = l & 15, c = l >> 4;
  const int b0 = blockIdx.y * 16;
  const int n0 = blockIdx.x * NPB + w * NPW;
  const short* Abase = (c & 1)  ? WL : WH;
  const short* Bbase = (c >> 1) ? XL : XH;

  f32x4 acc[N_OUT];
  const f32x4 zz = {0.f,0.f,0.f,0.f};
#pragma unroll
  for (int o=0;o<N_OUT;o++) acc[o] = zz;

  for (int nn=0; nn<NPW; ++nn) {
    const int n = n0 + nn;
    const bf16x8 bfrag = *(const bf16x8*)&Bbase[((size_t)n*B_ + b0 + bb)*8];
    const short* Ap = &Abase[(size_t)n*1280 + bb*8];
#pragma unroll
    for (int o=0;o<N_OUT;o++) {
      const bf16x8 afrag = *(const bf16x8*)&Ap[o*128];
      acc[o] = __builtin_amdgcn_mfma_f32_16x16x32_bf16(afrag, bfrag, acc[o], 0,0,0);
    }
  }

  const int slot = bb*4 + c;           // 0..63 contiguous per wave
  if (w) {
    f32x4* r = &red[(w-1)*640];
#pragma unroll
    for (int o=0;o<N_OUT;o++) r[o*64 + slot] = acc[o];
  }
  __syncthreads();
  if (!w) {
#pragma unroll
    for (int o=0;o<N_OUT;o++)
      acc[o] += red[o*64+slot] + red[640+o*64+slot] + red[1280+o*64+slot];
    float* Pp = &P[((size_t)blockIdx.x*B_ + b0 + bb)*OJ + c*4];
#pragma unroll
    for (int o=0;o<N_OUT;o++) *(f32x4*)&Pp[o*16] = acc[o];
  }
}

// ---- pass 2/3: u via MFMA, logits = u.veff (log2 domain), softmax, LDS tree -> P ----
__global__ __launch_bounds__(256) void pass23(const short* __restrict__ WH,
                                              const short* __restrict__ WL,
                                              const short* __restrict__ XH,
                                              const short* __restrict__ XL,
                                              const float* __restrict__ veff,
                                              float* __restrict__ P) {
  __shared__ f32x4 red[3*640];         // 30 KB
  const int tid = threadIdx.x, w = tid >> 6, l = tid & 63;
  const int bb = l & 15, c = l >> 4;
  const int b0 = blockIdx.y * 16;
  const int n0 = blockIdx.x * NPB + w * NPW;
  const short* Abase = (c & 1)  ? WL : WH;
  const short* Bbase = (c >> 1) ? XL : XH;

  f32x4 vj[N_OUT], acc[N_OUT];
  const f32x4 zz = {0.f,0.f,0.f,0.f};
  const float* vp = &veff[(size_t)(b0+bb)*OJ + c*4];
#pragma unroll
  for (int o=0;o<N_OUT;o++) { vj[o] = *(const f32x4*)&vp[o*16]; acc[o] = zz; }

  for (int nn=0; nn<NPW; ++nn) {
    const int n = n0 + nn;
    const bf16x8 bfrag = *(const bf16x8*)&Bbase[((size_t)n*B_ + b0 + bb)*8];
    const short* Ap = &Abase[(size_t)n*1280 + bb*8];
    f32x4 u[N_OUT];
#pragma unroll
    for (int o=0;o<N_OUT;o++) {
      const bf16x8 afrag = *(const bf16x8*)&Ap[o*128];
      u[o] = __builtin_amdgcn_mfma_f32_16x16x32_bf16(afrag, bfrag, zz, 0,0,0);
    }
    float ez[N_OUT], Z = 0.f;
#pragma unroll
    for (int o=0;o<N_OUT;o++) {
      float t = u[o][0]*vj[o][0] + u[o][1]*vj[o][1]
              + u[o][2]*vj[o][2] + u[o][3]*vj[o][3];
      t += __shfl_xor(t, 16);
      t += __shfl_xor(t, 32);
      ez[o] = exp2f(t);                // veff already in log2 domain
      Z += ez[o];
    }
    const float invZ = 1.f / Z;
#pragma unroll
    for (int o=0;o<N_OUT;o++) acc[o] += (ez[o] * invZ) * u[o];
  }

  const int slot = bb*4 + c;
  if (w) {
    f32x4* r = &red[(w-1)*640];
#pragma unroll
    for (int o=0;o<N_OUT;o++) r[o*64 + slot] = acc[o];
  }
  __syncthreads();
  if (!w) {
#pragma unroll
    for (int o=0;o<N_OUT;o++)
      acc[o] += red[o*64+slot] + red[640+o*64+slot] + red[1280+o*64+slot];
    float* Pp = &P[((size_t)blockIdx.x*B_ + b0 + bb)*OJ + c*4];
#pragma unroll
    for (int o=0;o<N_OUT;o++) *(f32x4*)&Pp[o*16] = acc[o];
  }
}

// ---- reduce partials over NGB + squash (+ optional vprev, output scaling) ----
__global__ __launch_bounds__(256) void finish(const float* __restrict__ P, float scale,
                                              const float* __restrict__ vprev,
                                              float* __restrict__ vout, float lscale) {
  const int idx = blockIdx.x*256 + threadIdx.x;      // b*160 + o*16 + j
  float t = 0.f;
#pragma unroll 8
  for (int g=0; g<NGB; ++g) t += P[(size_t)g*SN + idx];
  t *= scale;
  const float sq = row_sum16(t * t);                 // ||s||^2 over j
  float v = t * (sq / (1.f + sq)) * rsqrtf(sq + 1e-8f);
  v *= lscale;
  if (vprev != nullptr) v += vprev[idx];
  vout[idx] = v;
}

extern "C" void kernel_launch(void* const* d_in, const int* in_sizes, int n_in,
                              void* d_out, int out_size, void* d_ws, size_t ws_size,
                              hipStream_t stream) {
  const float* x = (const float*)d_in[0];   // (256,1152,8)
  const float* W = (const float*)d_in[1];   // (1,1152,10,16,8)
  float* out = (float*)d_out;               // (256,10,16)

  float* P   = (float*)d_ws;                // NGB*SN floats = 11.8 MB
  float* v1  = P  + (size_t)NGB*SN;         // stored * log2e
  float* v12 = v1 + SN;                     // stored * log2e
  short* WH = (short*)(v12 + SN);
  short* WL = WH + (size_t)NW_ELEMS*8;
  short* XH = WL + (size_t)NW_ELEMS*8;
  short* XL = XH + (size_t)(B_*N_IN)*8;     // total ws ~= 27.5 MB

  pack_all<<<NWB + XTB, 256, 0, stream>>>(W, x, WH, WL, XH, XL);

  const dim3 pg(NGB, 16), pb(256);

  // iter 1: uniform c -> P ; v1 = squash(0.1*s1)*log2e
  pass1<<<pg, pb, 0, stream>>>(WH, WL, XH, XL, P);
  finish<<<SN/256, 256, 0, stream>>>(P, 0.1f, nullptr, v1, LOG2E);

  // iter 2: logits = u.v1 -> P ; v12 = v1 + squash(s2)*log2e
  pass23<<<pg, pb, 0, stream>>>(WH, WL, XH, XL, v1, P);
  finish<<<SN/256, 256, 0, stream>>>(P, 1.0f, v1, v12, LOG2E);

  // iter 3: logits = u.(v1+v2) -> P ; out = squash(s3)
  pass23<<<pg, pb, 0, stream>>>(WH, WL, XH, XL, v12, P);
  finish<<<SN/256, 256, 0, stream>>>(P, 1.0f, nullptr, out, 1.0f);
}